// Round 3
// baseline (913.626 us; speedup 1.0000x reference)
//
#include <hip/hip_runtime.h>
#include <cstdint>

// Problem constants (from reference): B=16, S=4096, H=512, G=2, V=320, D=128
#define HDIM 512
#define GV   640
#define VNUM 320
#define DDIM 128
#define BM   32      // frames per block
#define BK   16      // K step

// Fused: GEMM (one group's 320 cols for 32 frames) + gumbel argmax + codes gather
// + noise-free softmax marginal accumulation.
// Thread map: 256 threads = 4 waves. Wave w owns rows w*8..w*8+7. Lane l owns
// columns l + 64*j (j=0..4). So each wave's lanes jointly hold the full 320
// logits of each of its 8 rows -> softmax/argmax are pure wave shuffles.
__global__ __launch_bounds__(256) void gvq_fused(
    const float* __restrict__ hidden,       // [nframes, 512]
    const float* __restrict__ Wm,           // [512, 640]
    const float* __restrict__ bias,         // [640]
    const float* __restrict__ codevectors,  // [640, 128]
    const float* __restrict__ gumbel_u,     // [nframes*2, 320]
    float* __restrict__ codes,              // [nframes, 256]
    float* __restrict__ marg_g)             // [640] global marginal accumulator
{
    __shared__ float As[BK][36];     // A tile transposed [k][row], pad to 36 for 16B-aligned rows
    __shared__ float Bs[BK][VNUM];   // B tile [k][col]
    __shared__ float marg_s[VNUM];

    const int t = threadIdx.x;
    const int w = t >> 6;        // wave 0..3
    const int l = t & 63;        // lane
    const int g = blockIdx.y;    // group 0/1
    const long frame0 = (long)blockIdx.x * BM;

    // NOTE: block has 256 threads but VNUM=320 — must stride! (round-2 bugfix:
    // previously columns 256..319 were never zeroed/flushed -> perplexity err 438)
    for (int c = t; c < VNUM; c += 256) marg_s[c] = 0.0f;

    float acc[8][5];
#pragma unroll
    for (int i = 0; i < 8; ++i)
#pragma unroll
        for (int j = 0; j < 5; ++j) acc[i][j] = 0.0f;

    const float* Wg = Wm + g * VNUM;
    const float* Ab = hidden + frame0 * HDIM;

    const int arow  = t >> 2;          // 0..63 (only t<128 used)
    const int akoff = (t & 3) << 2;    // 0,4,8,12
    const int bkr   = t >> 4;          // 0..15
    const int btcol = t & 15;

    for (int k0 = 0; k0 < HDIM; k0 += BK) {
        // --- stage A tile (32 rows x 16 k), transposed into As[k][row]
        if (t < 128) {
            float4 av = *(const float4*)(Ab + (long)arow * HDIM + k0 + akoff);
            As[akoff + 0][arow] = av.x;
            As[akoff + 1][arow] = av.y;
            As[akoff + 2][arow] = av.z;
            As[akoff + 3][arow] = av.w;
        }
        // --- stage B tile (16 k x 320 cols)
        {
            const float* src = Wg + (long)(k0 + bkr) * GV;
#pragma unroll
            for (int j = 0; j < 5; ++j) {
                int col = (btcol + (j << 4)) << 2;
                *(float4*)&Bs[bkr][col] = *(const float4*)(src + col);
            }
        }
        __syncthreads();
        // --- 8x5 register-tiled FMA
#pragma unroll
        for (int k = 0; k < BK; ++k) {
            float a[8], b[5];
            *(float4*)&a[0] = *(const float4*)&As[k][w * 8];      // broadcast reads
            *(float4*)&a[4] = *(const float4*)&As[k][w * 8 + 4];
#pragma unroll
            for (int j = 0; j < 5; ++j) b[j] = Bs[k][l + (j << 6)]; // 2-way bank alias = free
#pragma unroll
            for (int i = 0; i < 8; ++i)
#pragma unroll
                for (int j = 0; j < 5; ++j)
                    acc[i][j] = fmaf(a[i], b[j], acc[i][j]);
        }
        __syncthreads();
    }

    // ---------------- epilogue: per-row softmax / gumbel argmax / gather ----
    float bj[5];
#pragma unroll
    for (int j = 0; j < 5; ++j) bj[j] = bias[g * VNUM + l + (j << 6)];

    float macc[5] = {0.f, 0.f, 0.f, 0.f, 0.f};

#pragma unroll
    for (int i = 0; i < 8; ++i) {
        const long frame = frame0 + w * 8 + i;
        float z[5];
#pragma unroll
        for (int j = 0; j < 5; ++j) z[j] = acc[i][j] + bj[j];

        // noise-free softmax (for perplexity marginal)
        float mx = z[0];
#pragma unroll
        for (int j = 1; j < 5; ++j) mx = fmaxf(mx, z[j]);
        for (int off = 32; off > 0; off >>= 1)
            mx = fmaxf(mx, __shfl_xor(mx, off, 64));
        float e[5], s = 0.f;
#pragma unroll
        for (int j = 0; j < 5; ++j) { e[j] = __expf(z[j] - mx); s += e[j]; }
        for (int off = 32; off > 0; off >>= 1) s += __shfl_xor(s, off, 64);
        const float inv = 1.0f / s;
#pragma unroll
        for (int j = 0; j < 5; ++j) macc[j] += e[j] * inv;

        // gumbel-noised argmax (temperature is argmax-invariant)
        const float* up = gumbel_u + (frame * 2 + g) * (long)VNUM;
        float bv = -3.0e38f; int bc = 0x7fffffff;
#pragma unroll
        for (int j = 0; j < 5; ++j) {
            float u  = up[l + (j << 6)];
            float gz = z[j] - __logf(-__logf(u));
            if (gz > bv) { bv = gz; bc = l + (j << 6); }   // ascending v -> first-index tiebreak
        }
        for (int off = 32; off > 0; off >>= 1) {
            float ov = __shfl_xor(bv, off, 64);
            int   oc = __shfl_xor(bc, off, 64);
            if (ov > bv || (ov == bv && oc < bc)) { bv = ov; bc = oc; }
        }
        // codes = gathered codevector row (straight-through one-hot forward value)
        const float2* cv = (const float2*)(codevectors + ((long)g * VNUM + bc) * DDIM);
        float2* op = (float2*)(codes + frame * 256 + g * DDIM);
        op[l] = cv[l];
    }

    // block-local marginal -> global (strided: 256 threads, 320 columns)
#pragma unroll
    for (int j = 0; j < 5; ++j) atomicAdd(&marg_s[l + (j << 6)], macc[j]);
    __syncthreads();
    for (int c = t; c < VNUM; c += 256) atomicAdd(&marg_g[g * VNUM + c], marg_s[c]);
}

__global__ void gvq_zero(float* __restrict__ p, int n)
{
    int i = blockIdx.x * blockDim.x + threadIdx.x;
    if (i < n) p[i] = 0.0f;
}

// One wave: marginal[640] -> perplexity scalar
__global__ void gvq_perplexity(const float* __restrict__ marg_g,
                               float* __restrict__ out_scalar, float inv_n)
{
    const int l = threadIdx.x & 63;
    float total = 0.0f;
#pragma unroll
    for (int g = 0; g < 2; ++g) {
        float s = 0.0f;
#pragma unroll
        for (int j = 0; j < 5; ++j) {
            float m = marg_g[g * VNUM + l + (j << 6)] * inv_n;
            s += m * logf(m + 1e-7f);
        }
        for (int off = 32; off > 0; off >>= 1) s += __shfl_xor(s, off, 64);
        total += expf(-s);
    }
    if (l == 0) *out_scalar = total;
}

extern "C" void kernel_launch(void* const* d_in, const int* in_sizes, int n_in,
                              void* d_out, int out_size, void* d_ws, size_t ws_size,
                              hipStream_t stream)
{
    const float* hidden      = (const float*)d_in[0];
    const float* Wm          = (const float*)d_in[1];
    const float* bias        = (const float*)d_in[2];
    const float* codevectors = (const float*)d_in[3];
    const float* gumbel_u    = (const float*)d_in[4];
    float* out  = (float*)d_out;
    float* marg = (float*)d_ws;   // 640 floats of scratch

    const int nframes = in_sizes[0] / HDIM;   // 65536

    gvq_zero<<<1, GV, 0, stream>>>(marg, GV);

    dim3 grid(nframes / BM, 2);
    gvq_fused<<<grid, 256, 0, stream>>>(hidden, Wm, bias, codevectors, gumbel_u,
                                        out, marg);

    gvq_perplexity<<<1, 64, 0, stream>>>(marg, out + (long)nframes * 256,
                                         1.0f / (float)nframes);
}